// Round 8
// baseline (237.430 us; speedup 1.0000x reference)
//
#include <hip/hip_runtime.h>

// Problem constants: B=4, T=2048, D=1024, H=16, DK=64, M = B*T = 8192.
// Workspace layout (bytes):
//   xb  @ 0         : x as fp16            (16 MB)
//   wt  @ 16 MB     : Wq,Wk,Wv,Wo transposed [N][K] fp16 (4 x 2 MB)
//   q   @ 24 MB     : Q (pre-scaled by log2e/8) [B*T, D] fp16 (16 MB)
//   k   @ 40 MB     : K  [B*T, D] fp16     (16 MB)
//   v   @ 56 MB     : (unused now)
//   vt  @ 72 MB     : V^T [B*H][64][T] fp16(16 MB)  <- written by QKV epilogue
//   cx  @ 88 MB     : attention ctx fp16   (16 MB)
//   y   @ 104 MB    : pre-LN f32           (32 MB)

using u16 = unsigned short;
using u32 = unsigned int;
typedef _Float16 f16x8 __attribute__((ext_vector_type(8)));
typedef float f32x4 __attribute__((ext_vector_type(4)));
typedef unsigned short u16x8 __attribute__((ext_vector_type(8)));

template <bool B> struct BoolTag { static constexpr bool v = B; };

__device__ inline u16 f2h_bits(float f) {
    _Float16 h = (_Float16)f;
    return __builtin_bit_cast(u16, h);
}

__device__ __forceinline__ void gload16(const void* g, void* l) {
    __builtin_amdgcn_global_load_lds(
        (const __attribute__((address_space(1))) void*)g,
        (__attribute__((address_space(3))) void*)l, 16, 0, 0);
}

// ---------------------------------------------------------------- convert x
__global__ __launch_bounds__(256) void convert_x_kernel(const float* __restrict__ x,
                                                        u16* __restrict__ xb) {
    size_t i = ((size_t)blockIdx.x * 256 + threadIdx.x) * 8;
    float4 a = *(const float4*)(x + i);
    float4 b = *(const float4*)(x + i + 4);
    u16x8 o;
    o[0] = f2h_bits(a.x); o[1] = f2h_bits(a.y); o[2] = f2h_bits(a.z); o[3] = f2h_bits(a.w);
    o[4] = f2h_bits(b.x); o[5] = f2h_bits(b.y); o[6] = f2h_bits(b.z); o[7] = f2h_bits(b.w);
    *(u16x8*)(xb + i) = o;
}

// ------------------------------------------------ convert + transpose weight
__global__ __launch_bounds__(256) void convert_wt_kernel(const float* __restrict__ W,
                                                         u16* __restrict__ Wt) {
    __shared__ float ts[64][68];
    const int k0 = blockIdx.x * 64, n0 = blockIdx.y * 64;
    const int tid = threadIdx.x, rr = tid >> 3, c = tid & 7;
#pragma unroll
    for (int p = 0; p < 2; p++) {
        int k = p * 32 + rr;
        float4 u = *(const float4*)(W + (size_t)(k0 + k) * 1024 + n0 + c * 8);
        float4 w = *(const float4*)(W + (size_t)(k0 + k) * 1024 + n0 + c * 8 + 4);
        *(float4*)&ts[k][c * 8] = u;
        *(float4*)&ts[k][c * 8 + 4] = w;
    }
    __syncthreads();
#pragma unroll
    for (int p = 0; p < 2; p++) {
        int n = p * 32 + rr;
        u16 o[8];
#pragma unroll
        for (int j = 0; j < 8; j++) o[j] = f2h_bits(ts[c * 8 + j][n]);
        *(u16x8*)(Wt + (size_t)(n0 + n) * 1024 + k0 + c * 8) = *(u16x8*)o;
    }
}

// --------------------------------------------------------- 128x256 GEMM
// C[M,N] = A[M,1024] @ W (W as Wt[N][1024] fp16). BM=128, BN=256, BK=64.
// 512 threads = 8 waves (2M x 4N), per-wave 64x64. Triple-buffered LDS.
// MODE 0: QKV fused (N=3072): Q/K fp16 out + bias (+log2e/8 scale on Q);
//         V blocks transpose in-LDS and write vt[(b*16+h)*64+d][t] directly.
// MODE 1: Wo (N=1024), f32 out + bias + residual.
template <int MODE>
__global__ __launch_bounds__(512) void gemm256_kernel(
    const u16* __restrict__ A, const u16* __restrict__ Wt,
    const float* __restrict__ b0, const float* __restrict__ b1,
    const float* __restrict__ b2, u16* __restrict__ qo, u16* __restrict__ ko,
    u16* __restrict__ vt, float* __restrict__ outf,
    const float* __restrict__ xres) {
    constexpr int NBY = (MODE == 0) ? 12 : 4;
    __shared__ u16 As[3][128 * 64];
    __shared__ u16 Bs[3][256 * 64];

    const int bid = blockIdx.x;
    const int cpx = (MODE == 0) ? 96 : 32;        // gridDim/8, grid%8==0
    const int swz = (bid & 7) * cpx + (bid >> 3); // XCD-contiguous
    const int bx = swz / NBY, by = swz % NBY;
    const size_t row0 = (size_t)bx * 128;
    const size_t col0 = (size_t)by * 256;

    const int tid = threadIdx.x, lane = tid & 63;
    const int wid = tid >> 6, wm = wid >> 2, wn = wid & 3;
    const int l15 = lane & 15, lg = lane >> 4;
    const int rr = tid >> 3, c8 = tid & 7;
    const int scw = (c8 ^ (rr & 7)) * 8;          // pre-swizzled source chunk

    f32x4 acc[4][4] = {};

    auto stage_half = [&](int kt, u16* dA, u16* dB, int h) {
        const int k0 = kt * 64;
        if (h == 0) {
            gload16(A + (row0 + rr) * 1024 + k0 + scw, dA + tid * 8);
            gload16(Wt + (col0 + rr) * 1024 + k0 + scw, dB + tid * 8);
            gload16(Wt + (col0 + 64 + rr) * 1024 + k0 + scw, dB + (512 + tid) * 8);
        } else {
            gload16(A + (row0 + 64 + rr) * 1024 + k0 + scw, dA + (512 + tid) * 8);
            gload16(Wt + (col0 + 128 + rr) * 1024 + k0 + scw, dB + (1024 + tid) * 8);
            gload16(Wt + (col0 + 192 + rr) * 1024 + k0 + scw, dB + (1536 + tid) * 8);
        }
    };

    auto ldops = [&](const u16* bA, const u16* bB, int kcv, f16x8* Af, f16x8* Bf) {
        const int swo = ((kcv * 4 + lg) ^ (l15 & 7)) * 8;
#pragma unroll
        for (int n = 0; n < 4; n++)
            Bf[n] = *(const f16x8*)(bB + (wn * 64 + n * 16 + l15) * 64 + swo);
#pragma unroll
        for (int m = 0; m < 4; m++)
            Af[m] = *(const f16x8*)(bA + (wm * 64 + m * 16 + l15) * 64 + swo);
    };

    auto domfma = [&](const f16x8* Af, const f16x8* Bf) {
        __builtin_amdgcn_s_setprio(1);
#pragma unroll
        for (int m = 0; m < 4; m++)
#pragma unroll
            for (int n = 0; n < 4; n++)
                acc[m][n] = __builtin_amdgcn_mfma_f32_16x16x32_f16(
                    Af[m], Bf[n], acc[m][n], 0, 0, 0);
        __builtin_amdgcn_s_setprio(0);
    };

    u16 *pA = &As[0][0], *pnA = &As[1][0], *ppA = &As[2][0];
    u16 *pB = &Bs[0][0], *pnB = &Bs[1][0], *ppB = &Bs[2][0];

    stage_half(0, pA, pB, 0);
    stage_half(0, pA, pB, 1);
    stage_half(1, pnA, pnB, 0);
    stage_half(1, pnA, pnB, 1);
    asm volatile("s_waitcnt vmcnt(6)" ::: "memory");
    __builtin_amdgcn_sched_barrier(0);
    __builtin_amdgcn_s_barrier();

#pragma unroll 1
    for (int t = 0; t < 16; t++) {
        f16x8 af[4], bf[4];
        ldops(pA, pB, 0, af, bf);
        if (t < 14) stage_half(t + 2, ppA, ppB, 0);
        __builtin_amdgcn_sched_barrier(0);
        __builtin_amdgcn_s_barrier();
        asm volatile("s_waitcnt lgkmcnt(0)" ::: "memory");
        __builtin_amdgcn_sched_barrier(0);
        domfma(af, bf);
        __builtin_amdgcn_sched_barrier(0);
        __builtin_amdgcn_s_barrier();
        ldops(pA, pB, 1, af, bf);
        if (t < 14) stage_half(t + 2, ppA, ppB, 1);
        if (t < 14)       asm volatile("s_waitcnt vmcnt(6)" ::: "memory");
        else if (t == 14) asm volatile("s_waitcnt vmcnt(0)" ::: "memory");
        __builtin_amdgcn_sched_barrier(0);
        __builtin_amdgcn_s_barrier();
        asm volatile("s_waitcnt lgkmcnt(0)" ::: "memory");
        __builtin_amdgcn_sched_barrier(0);
        domfma(af, bf);
        __builtin_amdgcn_sched_barrier(0);
        if (t < 15) {
            __builtin_amdgcn_s_barrier();
            u16* tp;
            tp = pA; pA = pnA; pnA = ppA; ppA = tp;
            tp = pB; pB = pnB; pnB = ppB; ppB = tp;
        }
    }

    if (MODE == 0) {
        const int zsel = by >> 2;  // 0=Q, 1=K, 2=V
        if (zsel < 2) {
            u16* ob = zsel == 0 ? qo : ko;
            const float* bias = zsel == 0 ? b0 : b1;
            const float qs = zsel == 0 ? 0.18033688f : 1.0f;  // log2(e)/8 on Q
#pragma unroll
            for (int m = 0; m < 4; m++) {
#pragma unroll
                for (int n = 0; n < 4; n++) {
                    size_t col = col0 + wn * 64 + n * 16 + l15;
                    size_t colz = col & 1023;
                    float bb = bias[colz];
#pragma unroll
                    for (int r = 0; r < 4; r++) {
                        size_t row = row0 + wm * 64 + m * 16 + lg * 4 + r;
                        ob[row * 1024 + colz] = f2h_bits((acc[m][n][r] + bb) * qs);
                    }
                }
            }
        } else {
            // V: bias + in-LDS transpose -> vt[(b*16+h)*64+d][t]
            u16* TL = &Bs[0][0];  // [256][136] u16 = 69632 B (Bs is 98304 B)
            __syncthreads();
#pragma unroll
            for (int m = 0; m < 4; m++) {
#pragma unroll
                for (int n = 0; n < 4; n++) {
                    int cl = wn * 64 + n * 16 + l15;
                    float bb = b2[(col0 & 1023) + cl];
#pragma unroll
                    for (int r = 0; r < 4; r++) {
                        int rl = wm * 64 + m * 16 + lg * 4 + r;
                        TL[cl * 136 + rl] = f2h_bits(acc[m][n][r] + bb);
                    }
                }
            }
            __syncthreads();
            const int vrl = tid >> 1, th = tid & 1;
            size_t vrow = (row0 >> 11) * 1024 + (col0 & 1023) + vrl;
            const int t0loc = (int)(row0 & 2047) + th * 64;
#pragma unroll
            for (int j = 0; j < 8; j++)
                *(u16x8*)(vt + vrow * 2048 + t0loc + j * 8) =
                    *(const u16x8*)(TL + vrl * 136 + th * 64 + j * 8);
        }
    } else {
#pragma unroll
        for (int m = 0; m < 4; m++) {
#pragma unroll
            for (int n = 0; n < 4; n++) {
                size_t col = col0 + wn * 64 + n * 16 + l15;
                float bb = b0[col];
#pragma unroll
                for (int r = 0; r < 4; r++) {
                    size_t row = row0 + wm * 64 + m * 16 + lg * 4 + r;
                    size_t idx = row * 1024 + col;
                    outf[idx] = acc[m][n][r] + bb + xres[idx];
                }
            }
        }
    }
}

// ------------------------------------------------------------- attention v5
// Causal flash attention. 4 waves x 64 q rows = 256 q/block, KV steps of 64,
// grid (64 bh, 8 qb big-first) = 512 blocks. exp2-direct softmax (scale in Q).
// Swapped QK^T (mfma(K,Q)); P through padded per-wave LDS; row-sums via MFMA
// against a ones-fragment (accs) -> fully lane-local normalization, 0 shuffles.
// Main loop mask-free; 4-step uniformly-masked diagonal tail.
__global__ __launch_bounds__(256) void attn_kernel(const u16* __restrict__ Q,
                                                   const u16* __restrict__ Kb,
                                                   const u16* __restrict__ Vt,
                                                   u16* __restrict__ ctx) {
    __shared__ u16 Ks[2][64 * 64];
    __shared__ u16 Vs[2][64 * 64];
    __shared__ u16 Ps[4][4][16][68];  // [wave][qf][q=l15][64 k cols + pad]

    const int bh = blockIdx.x;
    const int b = bh >> 4, h = bh & 15;
    const int qb = 7 - (int)blockIdx.y;  // big blocks dispatch first
    const int tid = threadIdx.x, lane = tid & 63, wid = tid >> 6;
    const int l15 = lane & 15, lg = lane >> 4;
    const int q0w = qb * 256 + wid * 64;
    const int send = qb * 256;

    const int rr = tid >> 3, c8 = tid & 7;
    const int scw = (c8 ^ (rr & 7)) * 8;
    const size_t kbase = ((size_t)b * 2048) * 1024 + h * 64 + scw;
    const size_t vbase = ((size_t)bh * 64 + rr) * 2048 + scw;

    // Q fragments (B-operand), 4 q-tiles of 16
    f16x8 qv[4][2];
#pragma unroll
    for (int qf = 0; qf < 4; qf++) {
        size_t qoff = ((size_t)b * 2048 + q0w + qf * 16 + l15) * 1024 + h * 64 + lg * 8;
        qv[qf][0] = *(const f16x8*)(Q + qoff);
        qv[qf][1] = *(const f16x8*)(Q + qoff + 32);
    }

    const int swk0 = (lg ^ (l15 & 7)) * 8;
    const int swk1 = ((4 + lg) ^ (l15 & 7)) * 8;

    f16x8 ones;
#pragma unroll
    for (int j = 0; j < 8; j++) ones[j] = (_Float16)1.0f;

    f32x4 acc[4][4] = {};   // [qf][dt]
    f32x4 accs[4] = {};     // row-sums via ones-MFMA

    auto stage = [&](int s, int bf) {
#pragma unroll
        for (int ph = 0; ph < 2; ph++) {
            gload16(Kb + kbase + (size_t)(s + ph * 32 + rr) * 1024,
                    Ks[bf] + (ph * 256 + wid * 64) * 8);
            gload16(Vt + vbase + (size_t)(ph * 32) * 2048 + s,
                    Vs[bf] + (ph * 256 + wid * 64) * 8);
        }
    };

    auto body = [&](int s, int bf, auto maskc) {
        constexpr bool MASK = decltype(maskc)::v;
        // QK^T + softmax, one c-column tile at a time (keeps z transient)
#pragma unroll
        for (int c = 0; c < 4; c++) {
            const u16* kp = Ks[bf] + (c * 16 + l15) * 64;
            f16x8 kf0 = *(const f16x8*)(kp + swk0);
            f16x8 kf1 = *(const f16x8*)(kp + swk1);
#pragma unroll
            for (int qf = 0; qf < 4; qf++) {
                f32x4 z = {};
                z = __builtin_amdgcn_mfma_f32_16x16x32_f16(kf0, qv[qf][0], z, 0, 0, 0);
                z = __builtin_amdgcn_mfma_f32_16x16x32_f16(kf1, qv[qf][1], z, 0, 0, 0);
                float pv[4];
#pragma unroll
                for (int r = 0; r < 4; r++) {
                    float e = __builtin_amdgcn_exp2f(fminf(z[r], 15.0f));
                    if (MASK) {
                        int kk = s + c * 16 + lg * 4 + r;
                        e = (kk <= q0w + qf * 16 + l15) ? e : 0.0f;
                    }
                    pv[r] = e;
                }
                uint2 w;
                w.x = __builtin_bit_cast(u32, __builtin_amdgcn_cvt_pkrtz(pv[0], pv[1]));
                w.y = __builtin_bit_cast(u32, __builtin_amdgcn_cvt_pkrtz(pv[2], pv[3]));
                *(uint2*)(&Ps[wid][qf][l15][0] + c * 16 + lg * 4) = w;
            }
        }
        // P fragments
        f16x8 pa0[4], pa1[4];
#pragma unroll
        for (int qf = 0; qf < 4; qf++) {
            const u16* Pw = &Ps[wid][qf][l15][0];
            pa0[qf] = *(const f16x8*)(Pw + lg * 8);
            pa1[qf] = *(const f16x8*)(Pw + 32 + lg * 8);
        }
        // PV (V read once, used by all 4 qf) + row-sum MFMA
#pragma unroll
        for (int dt = 0; dt < 4; dt++) {
            const u16* vp = Vs[bf] + (dt * 16 + l15) * 64;
            f16x8 vf0 = *(const f16x8*)(vp + swk0);
            f16x8 vf1 = *(const f16x8*)(vp + swk1);
#pragma unroll
            for (int qf = 0; qf < 4; qf++) {
                acc[qf][dt] =
                    __builtin_amdgcn_mfma_f32_16x16x32_f16(pa0[qf], vf0, acc[qf][dt], 0, 0, 0);
                acc[qf][dt] =
                    __builtin_amdgcn_mfma_f32_16x16x32_f16(pa1[qf], vf1, acc[qf][dt], 0, 0, 0);
            }
        }
#pragma unroll
        for (int qf = 0; qf < 4; qf++) {
            accs[qf] = __builtin_amdgcn_mfma_f32_16x16x32_f16(pa0[qf], ones, accs[qf], 0, 0, 0);
            accs[qf] = __builtin_amdgcn_mfma_f32_16x16x32_f16(pa1[qf], ones, accs[qf], 0, 0, 0);
        }
    };

    stage(0, 0);
    int cur = 0;
    for (int s = 0; s < send; s += 64) {
        __syncthreads();
        stage(s + 64, cur ^ 1);
        body(s, cur, BoolTag<false>{});
        cur ^= 1;
    }
    // diagonal tail: 4 uniformly-masked steps (kv = send .. send+255)
#pragma unroll 1
    for (int j = 0; j < 4; j++) {
        __syncthreads();
        if (j < 3) stage(send + 64 * (j + 1), cur ^ 1);
        body(send + 64 * j, cur, BoolTag<true>{});
        cur ^= 1;
    }

    // normalize + write (all lane-local: accs rows match acc rows)
#pragma unroll
    for (int qf = 0; qf < 4; qf++) {
#pragma unroll
        for (int r = 0; r < 4; r++) {
            float inv = 1.0f / accs[qf][r];
            size_t row = (size_t)b * 2048 + q0w + qf * 16 + lg * 4 + r;
#pragma unroll
            for (int dt = 0; dt < 4; dt++)
                ctx[row * 1024 + h * 64 + dt * 16 + l15] = f2h_bits(acc[qf][dt][r] * inv);
        }
    }
}

// -------------------------------------------------------------- layer norm
__global__ __launch_bounds__(256) void ln_kernel(const float* __restrict__ y,
                                                 const float* __restrict__ g,
                                                 const float* __restrict__ bb,
                                                 float* __restrict__ out) {
    const int r = blockIdx.x, tid = threadIdx.x;
    float4 v = *(const float4*)(y + (size_t)r * 1024 + tid * 4);
    float s = v.x + v.y + v.z + v.w;
    float sq = v.x * v.x + v.y * v.y + v.z * v.z + v.w * v.w;
#pragma unroll
    for (int ofs = 1; ofs < 64; ofs <<= 1) {
        s += __shfl_xor(s, ofs);
        sq += __shfl_xor(sq, ofs);
    }
    __shared__ float as[4], aq[4];
    if ((tid & 63) == 0) { as[tid >> 6] = s; aq[tid >> 6] = sq; }
    __syncthreads();
    s = as[0] + as[1] + as[2] + as[3];
    sq = aq[0] + aq[1] + aq[2] + aq[3];
    float mu = s * (1.0f / 1024.0f);
    float var = sq * (1.0f / 1024.0f) - mu * mu;
    float rstd = rsqrtf(var + 1e-5f);
    float4 gv = *(const float4*)(g + tid * 4);
    float4 bv = *(const float4*)(bb + tid * 4);
    float4 o4;
    o4.x = (v.x - mu) * rstd * gv.x + bv.x;
    o4.y = (v.y - mu) * rstd * gv.y + bv.y;
    o4.z = (v.z - mu) * rstd * gv.z + bv.z;
    o4.w = (v.w - mu) * rstd * gv.w + bv.w;
    *(float4*)(out + (size_t)r * 1024 + tid * 4) = o4;
}

// ------------------------------------------------------------------ launch
extern "C" void kernel_launch(void* const* d_in, const int* in_sizes, int n_in,
                              void* d_out, int out_size, void* d_ws, size_t ws_size,
                              hipStream_t stream) {
    const float* x  = (const float*)d_in[0];
    const float* Wq = (const float*)d_in[1];
    const float* bq = (const float*)d_in[2];
    const float* Wk = (const float*)d_in[3];
    const float* bk = (const float*)d_in[4];
    const float* Wv = (const float*)d_in[5];
    const float* bv = (const float*)d_in[6];
    const float* Wo = (const float*)d_in[7];
    const float* bo = (const float*)d_in[8];
    const float* lg = (const float*)d_in[9];
    const float* lb = (const float*)d_in[10];
    float* out = (float*)d_out;

    char* ws = (char*)d_ws;
    u16* xb = (u16*)(ws + 0);
    u16* wt = (u16*)(ws + 16777216);
    u16* q  = (u16*)(ws + 25165824);
    u16* k  = (u16*)(ws + 41943040);
    u16* vt = (u16*)(ws + 75497472);
    u16* cx = (u16*)(ws + 92274688);
    float* y = (float*)(ws + 109051904);

    convert_x_kernel<<<4096, 256, 0, stream>>>(x, xb);
    dim3 gw(16, 16);
    convert_wt_kernel<<<gw, 256, 0, stream>>>(Wq, wt);
    convert_wt_kernel<<<gw, 256, 0, stream>>>(Wk, wt + 1048576);
    convert_wt_kernel<<<gw, 256, 0, stream>>>(Wv, wt + 2097152);
    convert_wt_kernel<<<gw, 256, 0, stream>>>(Wo, wt + 3145728);

    gemm256_kernel<0><<<768, 512, 0, stream>>>(xb, wt, bq, bk, bv, q, k, vt,
                                               nullptr, nullptr);
    attn_kernel<<<dim3(64, 8), 256, 0, stream>>>(q, k, vt, cx);
    gemm256_kernel<1><<<256, 512, 0, stream>>>(cx, wt + 3145728, bo, nullptr,
                                               nullptr, nullptr, nullptr, nullptr,
                                               y, x);
    ln_kernel<<<8192, 256, 0, stream>>>(y, lg, lb, out);
}

// Round 9
// 189.200 us; speedup vs baseline: 1.2549x; 1.2549x over previous
//
#include <hip/hip_runtime.h>

// Problem constants: B=4, T=2048, D=1024, H=16, DK=64, M = B*T = 8192.
// Workspace layout (bytes):
//   xb  @ 0         : x as fp16            (16 MB)
//   wt  @ 16 MB     : Wq,Wk,Wv,Wo transposed [N][K] fp16 (4 x 2 MB)
//   q   @ 24 MB     : Q (pre-scaled by log2e/8) [B*T, D] fp16 (16 MB)
//   k   @ 40 MB     : K  [B*T, D] fp16     (16 MB)
//   vt  @ 72 MB     : V^T [B*H][64][T] fp16(16 MB)  <- written by QKV epilogue
//   cx  @ 88 MB     : attention ctx fp16   (16 MB)
//   y   @ 104 MB    : pre-LN f32           (32 MB)

using u16 = unsigned short;
using u32 = unsigned int;
typedef _Float16 f16x8 __attribute__((ext_vector_type(8)));
typedef float f32x4 __attribute__((ext_vector_type(4)));
typedef unsigned short u16x8 __attribute__((ext_vector_type(8)));

template <bool B> struct BoolTag { static constexpr bool v = B; };

__device__ inline u16 f2h_bits(float f) {
    _Float16 h = (_Float16)f;
    return __builtin_bit_cast(u16, h);
}

__device__ __forceinline__ void gload16(const void* g, void* l) {
    __builtin_amdgcn_global_load_lds(
        (const __attribute__((address_space(1))) void*)g,
        (__attribute__((address_space(3))) void*)l, 16, 0, 0);
}

// ---------------------------------------------------------------- convert x
__global__ __launch_bounds__(256) void convert_x_kernel(const float* __restrict__ x,
                                                        u16* __restrict__ xb) {
    size_t i = ((size_t)blockIdx.x * 256 + threadIdx.x) * 8;
    float4 a = *(const float4*)(x + i);
    float4 b = *(const float4*)(x + i + 4);
    u16x8 o;
    o[0] = f2h_bits(a.x); o[1] = f2h_bits(a.y); o[2] = f2h_bits(a.z); o[3] = f2h_bits(a.w);
    o[4] = f2h_bits(b.x); o[5] = f2h_bits(b.y); o[6] = f2h_bits(b.z); o[7] = f2h_bits(b.w);
    *(u16x8*)(xb + i) = o;
}

// ------------------------------------- convert + transpose all 4 weights
__global__ __launch_bounds__(256) void convert_wt_kernel(
    const float* __restrict__ W0, const float* __restrict__ W1,
    const float* __restrict__ W2, const float* __restrict__ W3,
    u16* __restrict__ Wt) {
    __shared__ float ts[64][68];
    const int z = blockIdx.z;
    const float* W = z == 0 ? W0 : (z == 1 ? W1 : (z == 2 ? W2 : W3));
    u16* Wo = Wt + (size_t)z * 1048576;
    const int k0 = blockIdx.x * 64, n0 = blockIdx.y * 64;
    const int tid = threadIdx.x, rr = tid >> 3, c = tid & 7;
#pragma unroll
    for (int p = 0; p < 2; p++) {
        int k = p * 32 + rr;
        float4 u = *(const float4*)(W + (size_t)(k0 + k) * 1024 + n0 + c * 8);
        float4 w = *(const float4*)(W + (size_t)(k0 + k) * 1024 + n0 + c * 8 + 4);
        *(float4*)&ts[k][c * 8] = u;
        *(float4*)&ts[k][c * 8 + 4] = w;
    }
    __syncthreads();
#pragma unroll
    for (int p = 0; p < 2; p++) {
        int n = p * 32 + rr;
        u16 o[8];
#pragma unroll
        for (int j = 0; j < 8; j++) o[j] = f2h_bits(ts[c * 8 + j][n]);
        *(u16x8*)(Wo + (size_t)(n0 + n) * 1024 + k0 + c * 8) = *(u16x8*)o;
    }
}

// --------------------------------------------------------- 128x256 GEMM
// C[M,N] = A[M,1024] @ W (W as Wt[N][1024] fp16). BM=128, BN=256, BK=64.
// 512 threads = 8 waves (2M x 4N), per-wave 64x64. Triple-buffered LDS.
// MODE 0: QKV fused (N=3072): Q/K fp16 out + bias (+log2e/8 scale on Q);
//         V blocks transpose in-LDS and write vt[(b*16+h)*64+d][t] directly.
// MODE 1: Wo (N=1024), f32 out + bias + residual.
template <int MODE>
__global__ __launch_bounds__(512) void gemm256_kernel(
    const u16* __restrict__ A, const u16* __restrict__ Wt,
    const float* __restrict__ b0, const float* __restrict__ b1,
    const float* __restrict__ b2, u16* __restrict__ qo, u16* __restrict__ ko,
    u16* __restrict__ vt, float* __restrict__ outf,
    const float* __restrict__ xres) {
    constexpr int NBY = (MODE == 0) ? 12 : 4;
    __shared__ u16 As[3][128 * 64];
    __shared__ u16 Bs[3][256 * 64];

    const int bid = blockIdx.x;
    const int cpx = (MODE == 0) ? 96 : 32;        // gridDim/8, grid%8==0
    const int swz = (bid & 7) * cpx + (bid >> 3); // XCD-contiguous
    const int bx = swz / NBY, by = swz % NBY;
    const size_t row0 = (size_t)bx * 128;
    const size_t col0 = (size_t)by * 256;

    const int tid = threadIdx.x, lane = tid & 63;
    const int wid = tid >> 6, wm = wid >> 2, wn = wid & 3;
    const int l15 = lane & 15, lg = lane >> 4;
    const int rr = tid >> 3, c8 = tid & 7;
    const int scw = (c8 ^ (rr & 7)) * 8;          // pre-swizzled source chunk

    f32x4 acc[4][4] = {};

    auto stage_half = [&](int kt, u16* dA, u16* dB, int h) {
        const int k0 = kt * 64;
        if (h == 0) {
            gload16(A + (row0 + rr) * 1024 + k0 + scw, dA + tid * 8);
            gload16(Wt + (col0 + rr) * 1024 + k0 + scw, dB + tid * 8);
            gload16(Wt + (col0 + 64 + rr) * 1024 + k0 + scw, dB + (512 + tid) * 8);
        } else {
            gload16(A + (row0 + 64 + rr) * 1024 + k0 + scw, dA + (512 + tid) * 8);
            gload16(Wt + (col0 + 128 + rr) * 1024 + k0 + scw, dB + (1024 + tid) * 8);
            gload16(Wt + (col0 + 192 + rr) * 1024 + k0 + scw, dB + (1536 + tid) * 8);
        }
    };

    auto ldops = [&](const u16* bA, const u16* bB, int kcv, f16x8* Af, f16x8* Bf) {
        const int swo = ((kcv * 4 + lg) ^ (l15 & 7)) * 8;
#pragma unroll
        for (int n = 0; n < 4; n++)
            Bf[n] = *(const f16x8*)(bB + (wn * 64 + n * 16 + l15) * 64 + swo);
#pragma unroll
        for (int m = 0; m < 4; m++)
            Af[m] = *(const f16x8*)(bA + (wm * 64 + m * 16 + l15) * 64 + swo);
    };

    auto domfma = [&](const f16x8* Af, const f16x8* Bf) {
        __builtin_amdgcn_s_setprio(1);
#pragma unroll
        for (int m = 0; m < 4; m++)
#pragma unroll
            for (int n = 0; n < 4; n++)
                acc[m][n] = __builtin_amdgcn_mfma_f32_16x16x32_f16(
                    Af[m], Bf[n], acc[m][n], 0, 0, 0);
        __builtin_amdgcn_s_setprio(0);
    };

    u16 *pA = &As[0][0], *pnA = &As[1][0], *ppA = &As[2][0];
    u16 *pB = &Bs[0][0], *pnB = &Bs[1][0], *ppB = &Bs[2][0];

    stage_half(0, pA, pB, 0);
    stage_half(0, pA, pB, 1);
    stage_half(1, pnA, pnB, 0);
    stage_half(1, pnA, pnB, 1);
    asm volatile("s_waitcnt vmcnt(6)" ::: "memory");
    __builtin_amdgcn_sched_barrier(0);
    __builtin_amdgcn_s_barrier();

#pragma unroll 1
    for (int t = 0; t < 16; t++) {
        f16x8 af[4], bf[4];
        ldops(pA, pB, 0, af, bf);
        if (t < 14) stage_half(t + 2, ppA, ppB, 0);
        __builtin_amdgcn_sched_barrier(0);
        __builtin_amdgcn_s_barrier();
        asm volatile("s_waitcnt lgkmcnt(0)" ::: "memory");
        __builtin_amdgcn_sched_barrier(0);
        domfma(af, bf);
        __builtin_amdgcn_sched_barrier(0);
        __builtin_amdgcn_s_barrier();
        ldops(pA, pB, 1, af, bf);
        if (t < 14) stage_half(t + 2, ppA, ppB, 1);
        if (t < 14)       asm volatile("s_waitcnt vmcnt(6)" ::: "memory");
        else if (t == 14) asm volatile("s_waitcnt vmcnt(0)" ::: "memory");
        __builtin_amdgcn_sched_barrier(0);
        __builtin_amdgcn_s_barrier();
        asm volatile("s_waitcnt lgkmcnt(0)" ::: "memory");
        __builtin_amdgcn_sched_barrier(0);
        domfma(af, bf);
        __builtin_amdgcn_sched_barrier(0);
        if (t < 15) {
            __builtin_amdgcn_s_barrier();
            u16* tp;
            tp = pA; pA = pnA; pnA = ppA; ppA = tp;
            tp = pB; pB = pnB; pnB = ppB; ppB = tp;
        }
    }

    if (MODE == 0) {
        const int zsel = by >> 2;  // 0=Q, 1=K, 2=V
        if (zsel < 2) {
            u16* ob = zsel == 0 ? qo : ko;
            const float* bias = zsel == 0 ? b0 : b1;
            const float qs = zsel == 0 ? 0.18033688f : 1.0f;  // log2(e)/8 on Q
#pragma unroll
            for (int m = 0; m < 4; m++) {
#pragma unroll
                for (int n = 0; n < 4; n++) {
                    size_t col = col0 + wn * 64 + n * 16 + l15;
                    size_t colz = col & 1023;
                    float bb = bias[colz];
#pragma unroll
                    for (int r = 0; r < 4; r++) {
                        size_t row = row0 + wm * 64 + m * 16 + lg * 4 + r;
                        ob[row * 1024 + colz] = f2h_bits((acc[m][n][r] + bb) * qs);
                    }
                }
            }
        } else {
            // V: bias + in-LDS transpose -> vt[(b*16+h)*64+d][t]
            u16* TL = &Bs[0][0];  // [256][136] u16 = 69632 B (Bs is 98304 B)
            __syncthreads();
#pragma unroll
            for (int m = 0; m < 4; m++) {
#pragma unroll
                for (int n = 0; n < 4; n++) {
                    int cl = wn * 64 + n * 16 + l15;
                    float bb = b2[(col0 & 1023) + cl];
#pragma unroll
                    for (int r = 0; r < 4; r++) {
                        int rl = wm * 64 + m * 16 + lg * 4 + r;
                        TL[cl * 136 + rl] = f2h_bits(acc[m][n][r] + bb);
                    }
                }
            }
            __syncthreads();
            const int vrl = tid >> 1, th = tid & 1;
            size_t vrow = (row0 >> 11) * 1024 + (col0 & 1023) + vrl;
            const int t0loc = (int)(row0 & 2047) + th * 64;
#pragma unroll
            for (int j = 0; j < 8; j++)
                *(u16x8*)(vt + vrow * 2048 + t0loc + j * 8) =
                    *(const u16x8*)(TL + vrl * 136 + th * 64 + j * 8);
        }
    } else {
#pragma unroll
        for (int m = 0; m < 4; m++) {
#pragma unroll
            for (int n = 0; n < 4; n++) {
                size_t col = col0 + wn * 64 + n * 16 + l15;
                float bb = b0[col];
#pragma unroll
                for (int r = 0; r < 4; r++) {
                    size_t row = row0 + wm * 64 + m * 16 + lg * 4 + r;
                    size_t idx = row * 1024 + col;
                    outf[idx] = acc[m][n][r] + bb + xres[idx];
                }
            }
        }
    }
}

// ------------------------------------------------------------- attention v6
// v4b structure (proven) at 8 waves/block for TLP: 8 waves x 32 q = 256 q/block,
// KV steps of 64, grid (64 bh, 8 qb big-first) = 512 blocks = 2 clean rounds.
// exp2-direct softmax (scale folded into Q), swapped QK^T (mfma(K,Q)),
// cvt_pkrtz packed P stores into padded [16][72] per-wave-qf P-LDS.
// LDS 68 KB -> 2 blocks/CU = 16 waves/CU.
__global__ __launch_bounds__(512) void attn_kernel(const u16* __restrict__ Q,
                                                   const u16* __restrict__ Kb,
                                                   const u16* __restrict__ Vt,
                                                   u16* __restrict__ ctx) {
    __shared__ u16 Ks[2][64 * 64];
    __shared__ u16 Vs[2][64 * 64];
    __shared__ u16 Ps[8][2][16][72];  // [wave][qf][q=l15][64 k cols + pad]

    const int bh = blockIdx.x;
    const int b = bh >> 4, h = bh & 15;
    const int qb = 7 - (int)blockIdx.y;  // big blocks dispatch first
    const int tid = threadIdx.x, lane = tid & 63, wid = tid >> 6;
    const int l15 = lane & 15, lg = lane >> 4;
    const int q0w = qb * 256 + wid * 32;
    const int send = qb * 256;

    const int rr = tid >> 3, c8 = tid & 7;
    const int scw = (c8 ^ (rr & 7)) * 8;
    const size_t kbase = ((size_t)b * 2048) * 1024 + h * 64 + scw;
    const size_t vbase = ((size_t)bh * 64 + rr) * 2048 + scw;

    // Q fragments (B-operand), 2 q-tiles of 16
    f16x8 qv[2][2];
#pragma unroll
    for (int qf = 0; qf < 2; qf++) {
        size_t qoff = ((size_t)b * 2048 + q0w + qf * 16 + l15) * 1024 + h * 64 + lg * 8;
        qv[qf][0] = *(const f16x8*)(Q + qoff);
        qv[qf][1] = *(const f16x8*)(Q + qoff + 32);
    }

    const int swk0 = (lg ^ (l15 & 7)) * 8;
    const int swk1 = ((4 + lg) ^ (l15 & 7)) * 8;
    u16* Pw0 = &Ps[wid][0][0][0] + l15 * 72;
    u16* Pw1 = &Ps[wid][1][0][0] + l15 * 72;

    f32x4 acc[2][4] = {};
    float psum[2] = {0.0f, 0.0f};

    // 512 threads: one gload16 per thread covers a full 64x64 tile each
    auto stage = [&](int s, int bf) {
        gload16(Kb + kbase + (size_t)(s + rr) * 1024, Ks[bf] + tid * 8);
        gload16(Vt + vbase + s, Vs[bf] + tid * 8);
    };

    auto body = [&](int s, int bf, auto maskc) {
        constexpr bool MASK = decltype(maskc)::v;
        f32x4 sc[2][4];
#pragma unroll
        for (int c = 0; c < 4; c++) {
            const u16* kp = Ks[bf] + (c * 16 + l15) * 64;
            f16x8 kf0 = *(const f16x8*)(kp + swk0);
            f16x8 kf1 = *(const f16x8*)(kp + swk1);
#pragma unroll
            for (int qf = 0; qf < 2; qf++) {
                f32x4 z = {};
                z = __builtin_amdgcn_mfma_f32_16x16x32_f16(kf0, qv[qf][0], z, 0, 0, 0);
                z = __builtin_amdgcn_mfma_f32_16x16x32_f16(kf1, qv[qf][1], z, 0, 0, 0);
                sc[qf][c] = z;
            }
        }
#pragma unroll
        for (int qf = 0; qf < 2; qf++) {
            u16* Pw = qf ? Pw1 : Pw0;
#pragma unroll
            for (int c = 0; c < 4; c++) {
                float pv[4];
#pragma unroll
                for (int r = 0; r < 4; r++) {
                    float e = __builtin_amdgcn_exp2f(fminf(sc[qf][c][r], 15.0f));
                    if (MASK) {
                        int kk = s + c * 16 + lg * 4 + r;
                        e = (kk <= q0w + qf * 16 + l15) ? e : 0.0f;
                    }
                    psum[qf] += e;
                    pv[r] = e;
                }
                uint2 w;
                w.x = __builtin_bit_cast(u32, __builtin_amdgcn_cvt_pkrtz(pv[0], pv[1]));
                w.y = __builtin_bit_cast(u32, __builtin_amdgcn_cvt_pkrtz(pv[2], pv[3]));
                *(uint2*)(Pw + c * 16 + lg * 4) = w;
            }
        }
        f16x8 pa0[2], pa1[2];
#pragma unroll
        for (int qf = 0; qf < 2; qf++) {
            const u16* Pw = qf ? Pw1 : Pw0;
            pa0[qf] = *(const f16x8*)(Pw + lg * 8);
            pa1[qf] = *(const f16x8*)(Pw + 32 + lg * 8);
        }
#pragma unroll
        for (int dt = 0; dt < 4; dt++) {
            const u16* vp = Vs[bf] + (dt * 16 + l15) * 64;
            f16x8 vf0 = *(const f16x8*)(vp + swk0);
            f16x8 vf1 = *(const f16x8*)(vp + swk1);
#pragma unroll
            for (int qf = 0; qf < 2; qf++) {
                acc[qf][dt] =
                    __builtin_amdgcn_mfma_f32_16x16x32_f16(pa0[qf], vf0, acc[qf][dt], 0, 0, 0);
                acc[qf][dt] =
                    __builtin_amdgcn_mfma_f32_16x16x32_f16(pa1[qf], vf1, acc[qf][dt], 0, 0, 0);
            }
        }
    };

    stage(0, 0);
    int cur = 0;
    for (int s = 0; s < send; s += 64) {
        __syncthreads();
        stage(s + 64, cur ^ 1);
        body(s, cur, BoolTag<false>{});
        cur ^= 1;
    }
    // diagonal tail: 4 uniformly-synced masked steps; wave wid participates
    // in step j iff its q-range reaches kv block j (wid >= 2j).
#pragma unroll 1
    for (int j = 0; j < 4; j++) {
        __syncthreads();
        if (j < 3) stage(send + 64 * (j + 1), cur ^ 1);
        if (wid >= 2 * j) body(send + 64 * j, cur, BoolTag<true>{});
        cur ^= 1;
    }

    // row-sum reduce over the 4 lg-groups; redistribute per output row
#pragma unroll
    for (int qf = 0; qf < 2; qf++) {
        psum[qf] += __shfl_xor(psum[qf], 16);
        psum[qf] += __shfl_xor(psum[qf], 32);
    }
#pragma unroll
    for (int qf = 0; qf < 2; qf++) {
        float inv = 1.0f / psum[qf];
#pragma unroll
        for (int r = 0; r < 4; r++) {
            float ir = __shfl(inv, lg * 4 + r);
            size_t row = (size_t)b * 2048 + q0w + qf * 16 + lg * 4 + r;
#pragma unroll
            for (int dt = 0; dt < 4; dt++)
                ctx[row * 1024 + h * 64 + dt * 16 + l15] = f2h_bits(acc[qf][dt][r] * ir);
        }
    }
}

// -------------------------------------------------------------- layer norm
__global__ __launch_bounds__(256) void ln_kernel(const float* __restrict__ y,
                                                 const float* __restrict__ g,
                                                 const float* __restrict__ bb,
                                                 float* __restrict__ out) {
    const int r = blockIdx.x, tid = threadIdx.x;
    float4 v = *(const float4*)(y + (size_t)r * 1024 + tid * 4);
    float s = v.x + v.y + v.z + v.w;
    float sq = v.x * v.x + v.y * v.y + v.z * v.z + v.w * v.w;
#pragma unroll
    for (int ofs = 1; ofs < 64; ofs <<= 1) {
        s += __shfl_xor(s, ofs);
        sq += __shfl_xor(sq, ofs);
    }
    __shared__ float as[4], aq[4];
    if ((tid & 63) == 0) { as[tid >> 6] = s; aq[tid >> 6] = sq; }
    __syncthreads();
    s = as[0] + as[1] + as[2] + as[3];
    sq = aq[0] + aq[1] + aq[2] + aq[3];
    float mu = s * (1.0f / 1024.0f);
    float var = sq * (1.0f / 1024.0f) - mu * mu;
    float rstd = rsqrtf(var + 1e-5f);
    float4 gv = *(const float4*)(g + tid * 4);
    float4 bv = *(const float4*)(bb + tid * 4);
    float4 o4;
    o4.x = (v.x - mu) * rstd * gv.x + bv.x;
    o4.y = (v.y - mu) * rstd * gv.y + bv.y;
    o4.z = (v.z - mu) * rstd * gv.z + bv.z;
    o4.w = (v.w - mu) * rstd * gv.w + bv.w;
    *(float4*)(out + (size_t)r * 1024 + tid * 4) = o4;
}

// ------------------------------------------------------------------ launch
extern "C" void kernel_launch(void* const* d_in, const int* in_sizes, int n_in,
                              void* d_out, int out_size, void* d_ws, size_t ws_size,
                              hipStream_t stream) {
    const float* x  = (const float*)d_in[0];
    const float* Wq = (const float*)d_in[1];
    const float* bq = (const float*)d_in[2];
    const float* Wk = (const float*)d_in[3];
    const float* bk = (const float*)d_in[4];
    const float* Wv = (const float*)d_in[5];
    const float* bv = (const float*)d_in[6];
    const float* Wo = (const float*)d_in[7];
    const float* bo = (const float*)d_in[8];
    const float* lg = (const float*)d_in[9];
    const float* lb = (const float*)d_in[10];
    float* out = (float*)d_out;

    char* ws = (char*)d_ws;
    u16* xb = (u16*)(ws + 0);
    u16* wt = (u16*)(ws + 16777216);
    u16* q  = (u16*)(ws + 25165824);
    u16* k  = (u16*)(ws + 41943040);
    u16* vt = (u16*)(ws + 75497472);
    u16* cx = (u16*)(ws + 92274688);
    float* y = (float*)(ws + 109051904);

    convert_x_kernel<<<4096, 256, 0, stream>>>(x, xb);
    convert_wt_kernel<<<dim3(16, 16, 4), 256, 0, stream>>>(Wq, Wk, Wv, Wo, wt);

    gemm256_kernel<0><<<768, 512, 0, stream>>>(xb, wt, bq, bk, bv, q, k, vt,
                                               nullptr, nullptr);
    attn_kernel<<<dim3(64, 8), 512, 0, stream>>>(q, k, vt, cx);
    gemm256_kernel<1><<<256, 512, 0, stream>>>(cx, wt + 3145728, bo, nullptr,
                                               nullptr, nullptr, nullptr, nullptr,
                                               y, x);
    ln_kernel<<<8192, 256, 0, stream>>>(y, lg, lb, out);
}

// Round 10
// 188.413 us; speedup vs baseline: 1.2602x; 1.0042x over previous
//
#include <hip/hip_runtime.h>

// Problem constants: B=4, T=2048, D=1024, H=16, DK=64, M = B*T = 8192.
// Workspace layout (bytes):
//   xb  @ 0         : x as fp16            (16 MB)
//   wt  @ 16 MB     : Wq,Wk,Wv,Wo transposed [N][K] fp16 (4 x 2 MB)
//   q   @ 24 MB     : Q (pre-scaled by log2e/8) [B*T, D] fp16 (16 MB)
//   k   @ 40 MB     : K  [B*T, D] fp16     (16 MB)
//   vt  @ 72 MB     : V^T [B*H][64][T] fp16(16 MB)  <- written by QKV epilogue
//   cx  @ 88 MB     : attention ctx fp16   (16 MB)
//   y   @ 104 MB    : pre-LN f32           (32 MB)

using u16 = unsigned short;
using u32 = unsigned int;
typedef _Float16 f16x8 __attribute__((ext_vector_type(8)));
typedef float f32x4 __attribute__((ext_vector_type(4)));
typedef unsigned short u16x8 __attribute__((ext_vector_type(8)));

template <bool B> struct BoolTag { static constexpr bool v = B; };

__device__ inline u16 f2h_bits(float f) {
    _Float16 h = (_Float16)f;
    return __builtin_bit_cast(u16, h);
}

__device__ __forceinline__ void gload16(const void* g, void* l) {
    __builtin_amdgcn_global_load_lds(
        (const __attribute__((address_space(1))) void*)g,
        (__attribute__((address_space(3))) void*)l, 16, 0, 0);
}

#define PH_SYNC()                                            \
    __builtin_amdgcn_sched_barrier(0);                       \
    __builtin_amdgcn_s_barrier();                            \
    asm volatile("s_waitcnt lgkmcnt(0)" ::: "memory");       \
    __builtin_amdgcn_sched_barrier(0)
#define PH_END()                                             \
    __builtin_amdgcn_sched_barrier(0);                       \
    __builtin_amdgcn_s_barrier()

// ---------------------------------------------------------------- convert x
__global__ __launch_bounds__(256) void convert_x_kernel(const float* __restrict__ x,
                                                        u16* __restrict__ xb) {
    size_t i = ((size_t)blockIdx.x * 256 + threadIdx.x) * 8;
    float4 a = *(const float4*)(x + i);
    float4 b = *(const float4*)(x + i + 4);
    u16x8 o;
    o[0] = f2h_bits(a.x); o[1] = f2h_bits(a.y); o[2] = f2h_bits(a.z); o[3] = f2h_bits(a.w);
    o[4] = f2h_bits(b.x); o[5] = f2h_bits(b.y); o[6] = f2h_bits(b.z); o[7] = f2h_bits(b.w);
    *(u16x8*)(xb + i) = o;
}

// ------------------------------------- convert + transpose all 4 weights
__global__ __launch_bounds__(256) void convert_wt_kernel(
    const float* __restrict__ W0, const float* __restrict__ W1,
    const float* __restrict__ W2, const float* __restrict__ W3,
    u16* __restrict__ Wt) {
    __shared__ float ts[64][68];
    const int z = blockIdx.z;
    const float* W = z == 0 ? W0 : (z == 1 ? W1 : (z == 2 ? W2 : W3));
    u16* Wo = Wt + (size_t)z * 1048576;
    const int k0 = blockIdx.x * 64, n0 = blockIdx.y * 64;
    const int tid = threadIdx.x, rr = tid >> 3, c = tid & 7;
#pragma unroll
    for (int p = 0; p < 2; p++) {
        int k = p * 32 + rr;
        float4 u = *(const float4*)(W + (size_t)(k0 + k) * 1024 + n0 + c * 8);
        float4 w = *(const float4*)(W + (size_t)(k0 + k) * 1024 + n0 + c * 8 + 4);
        *(float4*)&ts[k][c * 8] = u;
        *(float4*)&ts[k][c * 8 + 4] = w;
    }
    __syncthreads();
#pragma unroll
    for (int p = 0; p < 2; p++) {
        int n = p * 32 + rr;
        u16 o[8];
#pragma unroll
        for (int j = 0; j < 8; j++) o[j] = f2h_bits(ts[c * 8 + j][n]);
        *(u16x8*)(Wo + (size_t)(n0 + n) * 1024 + k0 + c * 8) = *(u16x8*)o;
    }
}

// --------------------------------------------- 256x256 8-phase QKV GEMM
// C[8192,3072] = xb @ [Wq|Wk|Wv] (Wt[N][K] fp16). BM=BN=256, BK=64.
// 512 threads = 8 waves (2M x 4N), per-wave 128x64 (8x4 16x16x32 frags).
// Double-buffered 128 KB LDS: even K-tiles -> buf0, odd -> buf1.
// 8 phases / 2 K-tiles; phase = {ds_reads (+4 staging gloads early in the
// window) -> barrier -> lgkmcnt(0) -> setprio(1) 16 MFMA setprio(0) ->
// barrier}. B-frags reused across the two M-half phases (24 reads/K-tile).
// vmcnt(0) gates at Ph4/Ph8 wait on loads issued 2-3 phases earlier.
// Epilogue: Q/K fp16+bias (Q scaled log2e/8); V transposed in-LDS -> vt.
__global__ __launch_bounds__(512) void gemm_qkv256_kernel(
    const u16* __restrict__ A, const u16* __restrict__ Wt,
    const float* __restrict__ bq, const float* __restrict__ bk,
    const float* __restrict__ bv, u16* __restrict__ qo, u16* __restrict__ ko,
    u16* __restrict__ vt) {
    __shared__ u16 SH[65536];  // 128 KB
    u16* const Ab0 = SH;
    u16* const Ab1 = SH + 16384;
    u16* const Bb0 = SH + 32768;
    u16* const Bb1 = SH + 49152;

    const int bid = blockIdx.x;                    // 384 = 32 x 12, %8==0
    const int swz = (bid & 7) * 48 + (bid >> 3);   // XCD-contiguous
    const int bx = swz / 12, by = swz % 12;
    const size_t row0 = (size_t)bx * 256;
    const size_t col0 = (size_t)by * 256;

    const int tid = threadIdx.x, lane = tid & 63;
    const int wid = tid >> 6, wm = wid >> 2, wn = wid & 3;
    const int l15 = lane & 15, lg = lane >> 4;
    const int rr = tid >> 3, c8 = tid & 7;
    const int scw = (c8 ^ (rr & 7)) * 8;           // pre-swizzled source chunk

    f32x4 acc[8][4] = {};
    f16x8 af[4], bf[4];

    auto stageA = [&](int kt, u16* dst) {
#pragma unroll
        for (int g = 0; g < 4; g++)
            gload16(A + (row0 + g * 64 + rr) * 1024 + kt * 64 + scw,
                    dst + (g * 512 + tid) * 8);
    };
    auto stageB = [&](int kt, u16* dst) {
#pragma unroll
        for (int g = 0; g < 4; g++)
            gload16(Wt + (col0 + g * 64 + rr) * 1024 + kt * 64 + scw,
                    dst + (g * 512 + tid) * 8);
    };
    auto ldB4 = [&](const u16* Bb, int kc) {
#pragma unroll
        for (int n = 0; n < 4; n++) {
            int rb = wn * 64 + n * 16 + l15;
            bf[n] = *(const f16x8*)(Bb + rb * 64 + ((kc * 4 + lg) ^ (rb & 7)) * 8);
        }
    };
    auto ldA4 = [&](const u16* Abf, int kc, int half) {
#pragma unroll
        for (int m = 0; m < 4; m++) {
            int ra = wm * 128 + half * 64 + m * 16 + l15;
            af[m] = *(const f16x8*)(Abf + ra * 64 + ((kc * 4 + lg) ^ (ra & 7)) * 8);
        }
    };
    auto mf16 = [&](int half) {
        __builtin_amdgcn_s_setprio(1);
#pragma unroll
        for (int m = 0; m < 4; m++)
#pragma unroll
            for (int n = 0; n < 4; n++)
                acc[half * 4 + m][n] = __builtin_amdgcn_mfma_f32_16x16x32_f16(
                    af[m], bf[n], acc[half * 4 + m][n], 0, 0, 0);
        __builtin_amdgcn_s_setprio(0);
    };

    // prologue: K-tile 0 -> buf0, K-tile 1 -> buf1
    stageA(0, Ab0); stageB(0, Bb0);
    stageA(1, Ab1); stageB(1, Bb1);
    asm volatile("s_waitcnt vmcnt(8)" ::: "memory");  // K-tile 0 landed
    __builtin_amdgcn_sched_barrier(0);
    __builtin_amdgcn_s_barrier();

#pragma unroll 1
    for (int t = 0; t < 8; t++) {
        // Ph1: buf0 kc0 Mlow; stage A(2t+1)->buf1 (t>=1; t=0 pre-staged)
        ldB4(Bb0, 0); ldA4(Ab0, 0, 0);
        if (t >= 1) stageA(2 * t + 1, Ab1);
        PH_SYNC(); mf16(0); PH_END();
        // Ph2: buf0 kc0 Mhigh (bf reused); stage B(2t+1)->buf1
        ldA4(Ab0, 0, 1);
        if (t >= 1) stageB(2 * t + 1, Bb1);
        PH_SYNC(); mf16(1); PH_END();
        // Ph3: buf0 kc1 Mlow
        ldB4(Bb0, 1); ldA4(Ab0, 1, 0);
        PH_SYNC(); mf16(0); PH_END();
        // Ph4: buf0 kc1 Mhigh; gate: buf1 staging (issued Ph1-2) landed
        ldA4(Ab0, 1, 1);
        asm volatile("s_waitcnt vmcnt(0)" ::: "memory");
        PH_SYNC(); mf16(1); PH_END();
        // Ph5: buf1 kc0 Mlow; stage A(2t+2)->buf0 (t<7)
        ldB4(Bb1, 0); ldA4(Ab1, 0, 0);
        if (t < 7) stageA(2 * t + 2, Ab0);
        PH_SYNC(); mf16(0); PH_END();
        // Ph6: buf1 kc0 Mhigh; stage B(2t+2)->buf0
        ldA4(Ab1, 0, 1);
        if (t < 7) stageB(2 * t + 2, Bb0);
        PH_SYNC(); mf16(1); PH_END();
        // Ph7: buf1 kc1 Mlow
        ldB4(Bb1, 1); ldA4(Ab1, 1, 0);
        PH_SYNC(); mf16(0); PH_END();
        // Ph8: buf1 kc1 Mhigh; gate: buf0 staging (issued Ph5-6) landed
        ldA4(Ab1, 1, 1);
        asm volatile("s_waitcnt vmcnt(0)" ::: "memory");
        PH_SYNC(); mf16(1); PH_END();
    }

    const int zsel = by >> 2;  // 0=Q, 1=K, 2=V
    if (zsel < 2) {
        u16* ob = zsel == 0 ? qo : ko;
        const float* bias = zsel == 0 ? bq : bk;
        const float qs = zsel == 0 ? 0.18033688f : 1.0f;  // log2(e)/8 on Q
#pragma unroll
        for (int m = 0; m < 8; m++) {
#pragma unroll
            for (int n = 0; n < 4; n++) {
                size_t col = col0 + wn * 64 + n * 16 + l15;
                size_t colz = col & 1023;
                float bb = bias[colz];
#pragma unroll
                for (int r = 0; r < 4; r++) {
                    size_t row = row0 + wm * 128 + m * 16 + lg * 4 + r;
                    ob[row * 1024 + colz] = f2h_bits((acc[m][n][r] + bb) * qs);
                }
            }
        }
    } else {
        // V: bias + in-LDS transpose (two 128-row halves) -> vt[b*1024+d][t]
        const int dz0 = (by - 8) * 256;
        const int b = bx >> 3;
        const int tloc = (bx & 7) * 256;
        const int vcl = tid >> 1, th = tid & 1;
#pragma unroll 1
        for (int h = 0; h < 2; h++) {
            __syncthreads();
            if (wm == h) {
#pragma unroll
                for (int m = 0; m < 8; m++) {
#pragma unroll
                    for (int n = 0; n < 4; n++) {
                        int cl = wn * 64 + n * 16 + l15;
                        float bb = bv[dz0 + cl];
#pragma unroll
                        for (int r = 0; r < 4; r++) {
                            int rl = m * 16 + lg * 4 + r;
                            SH[cl * 136 + rl] = f2h_bits(acc[m][n][r] + bb);
                        }
                    }
                }
            }
            __syncthreads();
            size_t vrow = (size_t)b * 1024 + dz0 + vcl;
#pragma unroll
            for (int j = 0; j < 8; j++)
                *(u16x8*)(vt + vrow * 2048 + tloc + h * 128 + th * 64 + j * 8) =
                    *(const u16x8*)(SH + vcl * 136 + th * 64 + j * 8);
        }
    }
}

// ------------------------------------------------------------- Wo GEMM
// y[f32] = cx @ Wo + bo + x. BM=128, BN=256, BK=64, 8 waves, per-wave 64x64.
// Triple-buffered, m201-style phases. 256 blocks = 1 clean round.
__global__ __launch_bounds__(512) void gemm_wo_kernel(
    const u16* __restrict__ A, const u16* __restrict__ Wt,
    const float* __restrict__ b0, float* __restrict__ outf,
    const float* __restrict__ xres) {
    __shared__ u16 As[3][128 * 64];
    __shared__ u16 Bs[3][256 * 64];

    const int bid = blockIdx.x;
    const int swz = (bid & 7) * 32 + (bid >> 3);
    const int bx = swz / 4, by = swz % 4;
    const size_t row0 = (size_t)bx * 128;
    const size_t col0 = (size_t)by * 256;

    const int tid = threadIdx.x, lane = tid & 63;
    const int wid = tid >> 6, wm = wid >> 2, wn = wid & 3;
    const int l15 = lane & 15, lg = lane >> 4;
    const int rr = tid >> 3, c8 = tid & 7;
    const int scw = (c8 ^ (rr & 7)) * 8;

    f32x4 acc[4][4] = {};

    auto stage_half = [&](int kt, u16* dA, u16* dB, int h) {
        const int k0 = kt * 64;
        if (h == 0) {
            gload16(A + (row0 + rr) * 1024 + k0 + scw, dA + tid * 8);
            gload16(Wt + (col0 + rr) * 1024 + k0 + scw, dB + tid * 8);
            gload16(Wt + (col0 + 64 + rr) * 1024 + k0 + scw, dB + (512 + tid) * 8);
        } else {
            gload16(A + (row0 + 64 + rr) * 1024 + k0 + scw, dA + (512 + tid) * 8);
            gload16(Wt + (col0 + 128 + rr) * 1024 + k0 + scw, dB + (1024 + tid) * 8);
            gload16(Wt + (col0 + 192 + rr) * 1024 + k0 + scw, dB + (1536 + tid) * 8);
        }
    };

    auto ldops = [&](const u16* bA, const u16* bB, int kcv, f16x8* Af, f16x8* Bf) {
        const int swo = ((kcv * 4 + lg) ^ (l15 & 7)) * 8;
#pragma unroll
        for (int n = 0; n < 4; n++)
            Bf[n] = *(const f16x8*)(bB + (wn * 64 + n * 16 + l15) * 64 + swo);
#pragma unroll
        for (int m = 0; m < 4; m++)
            Af[m] = *(const f16x8*)(bA + (wm * 64 + m * 16 + l15) * 64 + swo);
    };

    auto domfma = [&](const f16x8* Af, const f16x8* Bf) {
        __builtin_amdgcn_s_setprio(1);
#pragma unroll
        for (int m = 0; m < 4; m++)
#pragma unroll
            for (int n = 0; n < 4; n++)
                acc[m][n] = __builtin_amdgcn_mfma_f32_16x16x32_f16(
                    Af[m], Bf[n], acc[m][n], 0, 0, 0);
        __builtin_amdgcn_s_setprio(0);
    };

    u16 *pA = &As[0][0], *pnA = &As[1][0], *ppA = &As[2][0];
    u16 *pB = &Bs[0][0], *pnB = &Bs[1][0], *ppB = &Bs[2][0];

    stage_half(0, pA, pB, 0);
    stage_half(0, pA, pB, 1);
    stage_half(1, pnA, pnB, 0);
    stage_half(1, pnA, pnB, 1);
    asm volatile("s_waitcnt vmcnt(6)" ::: "memory");
    __builtin_amdgcn_sched_barrier(0);
    __builtin_amdgcn_s_barrier();

#pragma unroll 1
    for (int t = 0; t < 16; t++) {
        f16x8 af[4], bf[4];
        ldops(pA, pB, 0, af, bf);
        if (t < 14) stage_half(t + 2, ppA, ppB, 0);
        PH_SYNC(); domfma(af, bf); PH_END();
        ldops(pA, pB, 1, af, bf);
        if (t < 14) stage_half(t + 2, ppA, ppB, 1);
        if (t < 14)       asm volatile("s_waitcnt vmcnt(6)" ::: "memory");
        else if (t == 14) asm volatile("s_waitcnt vmcnt(0)" ::: "memory");
        PH_SYNC(); domfma(af, bf);
        __builtin_amdgcn_sched_barrier(0);
        if (t < 15) {
            __builtin_amdgcn_s_barrier();
            u16* tp;
            tp = pA; pA = pnA; pnA = ppA; ppA = tp;
            tp = pB; pB = pnB; pnB = ppB; ppB = tp;
        }
    }

#pragma unroll
    for (int m = 0; m < 4; m++) {
#pragma unroll
        for (int n = 0; n < 4; n++) {
            size_t col = col0 + wn * 64 + n * 16 + l15;
            float bb = b0[col];
#pragma unroll
            for (int r = 0; r < 4; r++) {
                size_t row = row0 + wm * 64 + m * 16 + lg * 4 + r;
                size_t idx = row * 1024 + col;
                outf[idx] = acc[m][n][r] + bb + xres[idx];
            }
        }
    }
}

// ------------------------------------------------------------- attention v6
// 8 waves x 32 q = 256 q/block, KV steps of 64, grid (64 bh, 8 qb big-first)
// = 512 blocks = 2 clean rounds. exp2-direct softmax (scale folded into Q),
// swapped QK^T (mfma(K,Q)), cvt_pkrtz packed P into padded [16][72] P-LDS.
// LDS 68 KB -> 2 blocks/CU = 16 waves/CU.
__global__ __launch_bounds__(512) void attn_kernel(const u16* __restrict__ Q,
                                                   const u16* __restrict__ Kb,
                                                   const u16* __restrict__ Vt,
                                                   u16* __restrict__ ctx) {
    __shared__ u16 Ks[2][64 * 64];
    __shared__ u16 Vs[2][64 * 64];
    __shared__ u16 Ps[8][2][16][72];

    const int bh = blockIdx.x;
    const int b = bh >> 4, h = bh & 15;
    const int qb = 7 - (int)blockIdx.y;  // big blocks dispatch first
    const int tid = threadIdx.x, lane = tid & 63, wid = tid >> 6;
    const int l15 = lane & 15, lg = lane >> 4;
    const int q0w = qb * 256 + wid * 32;
    const int send = qb * 256;

    const int rr = tid >> 3, c8 = tid & 7;
    const int scw = (c8 ^ (rr & 7)) * 8;
    const size_t kbase = ((size_t)b * 2048) * 1024 + h * 64 + scw;
    const size_t vbase = ((size_t)bh * 64 + rr) * 2048 + scw;

    f16x8 qv[2][2];
#pragma unroll
    for (int qf = 0; qf < 2; qf++) {
        size_t qoff = ((size_t)b * 2048 + q0w + qf * 16 + l15) * 1024 + h * 64 + lg * 8;
        qv[qf][0] = *(const f16x8*)(Q + qoff);
        qv[qf][1] = *(const f16x8*)(Q + qoff + 32);
    }

    const int swk0 = (lg ^ (l15 & 7)) * 8;
    const int swk1 = ((4 + lg) ^ (l15 & 7)) * 8;
    u16* Pw0 = &Ps[wid][0][0][0] + l15 * 72;
    u16* Pw1 = &Ps[wid][1][0][0] + l15 * 72;

    f32x4 acc[2][4] = {};
    float psum[2] = {0.0f, 0.0f};

    auto stage = [&](int s, int bf) {
        gload16(Kb + kbase + (size_t)(s + rr) * 1024, Ks[bf] + tid * 8);
        gload16(Vt + vbase + s, Vs[bf] + tid * 8);
    };

    auto body = [&](int s, int bf, auto maskc) {
        constexpr bool MASK = decltype(maskc)::v;
        f32x4 sc[2][4];
#pragma unroll
        for (int c = 0; c < 4; c++) {
            const u16* kp = Ks[bf] + (c * 16 + l15) * 64;
            f16x8 kf0 = *(const f16x8*)(kp + swk0);
            f16x8 kf1 = *(const f16x8*)(kp + swk1);
#pragma unroll
            for (int qf = 0; qf < 2; qf++) {
                f32x4 z = {};
                z = __builtin_amdgcn_mfma_f32_16x16x32_f16(kf0, qv[qf][0], z, 0, 0, 0);
                z = __builtin_amdgcn_mfma_f32_16x16x32_f16(kf1, qv[qf][1], z, 0, 0, 0);
                sc[qf][c] = z;
            }
        }
#pragma unroll
        for (int qf = 0; qf < 2; qf++) {
            u16* Pw = qf ? Pw1 : Pw0;
#pragma unroll
            for (int c = 0; c < 4; c++) {
                float pv[4];
#pragma unroll
                for (int r = 0; r < 4; r++) {
                    float e = __builtin_amdgcn_exp2f(fminf(sc[qf][c][r], 15.0f));
                    if (MASK) {
                        int kk = s + c * 16 + lg * 4 + r;
                        e = (kk <= q0w + qf * 16 + l15) ? e : 0.0f;
                    }
                    psum[qf] += e;
                    pv[r] = e;
                }
                uint2 w;
                w.x = __builtin_bit_cast(u32, __builtin_amdgcn_cvt_pkrtz(pv[0], pv[1]));
                w.y = __builtin_bit_cast(u32, __builtin_amdgcn_cvt_pkrtz(pv[2], pv[3]));
                *(uint2*)(Pw + c * 16 + lg * 4) = w;
            }
        }
        f16x8 pa0[2], pa1[2];
#pragma unroll
        for (int qf = 0; qf < 2; qf++) {
            const u16* Pw = qf ? Pw1 : Pw0;
            pa0[qf] = *(const f16x8*)(Pw + lg * 8);
            pa1[qf] = *(const f16x8*)(Pw + 32 + lg * 8);
        }
#pragma unroll
        for (int dt = 0; dt < 4; dt++) {
            const u16* vp = Vs[bf] + (dt * 16 + l15) * 64;
            f16x8 vf0 = *(const f16x8*)(vp + swk0);
            f16x8 vf1 = *(const f16x8*)(vp + swk1);
#pragma unroll
            for (int qf = 0; qf < 2; qf++) {
                acc[qf][dt] =
                    __builtin_amdgcn_mfma_f32_16x16x32_f16(pa0[qf], vf0, acc[qf][dt], 0, 0, 0);
                acc[qf][dt] =
                    __builtin_amdgcn_mfma_f32_16x16x32_f16(pa1[qf], vf1, acc[qf][dt], 0, 0, 0);
            }
        }
    };

    stage(0, 0);
    int cur = 0;
    for (int s = 0; s < send; s += 64) {
        __syncthreads();
        stage(s + 64, cur ^ 1);
        body(s, cur, BoolTag<false>{});
        cur ^= 1;
    }
#pragma unroll 1
    for (int j = 0; j < 4; j++) {
        __syncthreads();
        if (j < 3) stage(send + 64 * (j + 1), cur ^ 1);
        if (wid >= 2 * j) body(send + 64 * j, cur, BoolTag<true>{});
        cur ^= 1;
    }

#pragma unroll
    for (int qf = 0; qf < 2; qf++) {
        psum[qf] += __shfl_xor(psum[qf], 16);
        psum[qf] += __shfl_xor(psum[qf], 32);
    }
#pragma unroll
    for (int qf = 0; qf < 2; qf++) {
        float inv = 1.0f / psum[qf];
#pragma unroll
        for (int r = 0; r < 4; r++) {
            float ir = __shfl(inv, lg * 4 + r);
            size_t row = (size_t)b * 2048 + q0w + qf * 16 + lg * 4 + r;
#pragma unroll
            for (int dt = 0; dt < 4; dt++)
                ctx[row * 1024 + h * 64 + dt * 16 + l15] = f2h_bits(acc[qf][dt][r] * ir);
        }
    }
}

// -------------------------------------------------------------- layer norm
__global__ __launch_bounds__(256) void ln_kernel(const float* __restrict__ y,
                                                 const float* __restrict__ g,
                                                 const float* __restrict__ bb,
                                                 float* __restrict__ out) {
    const int r = blockIdx.x, tid = threadIdx.x;
    float4 v = *(const float4*)(y + (size_t)r * 1024 + tid * 4);
    float s = v.x + v.y + v.z + v.w;
    float sq = v.x * v.x + v.y * v.y + v.z * v.z + v.w * v.w;
#pragma unroll
    for (int ofs = 1; ofs < 64; ofs <<= 1) {
        s += __shfl_xor(s, ofs);
        sq += __shfl_xor(sq, ofs);
    }
    __shared__ float as[4], aq[4];
    if ((tid & 63) == 0) { as[tid >> 6] = s; aq[tid >> 6] = sq; }
    __syncthreads();
    s = as[0] + as[1] + as[2] + as[3];
    sq = aq[0] + aq[1] + aq[2] + aq[3];
    float mu = s * (1.0f / 1024.0f);
    float var = sq * (1.0f / 1024.0f) - mu * mu;
    float rstd = rsqrtf(var + 1e-5f);
    float4 gv = *(const float4*)(g + tid * 4);
    float4 bv = *(const float4*)(bb + tid * 4);
    float4 o4;
    o4.x = (v.x - mu) * rstd * gv.x + bv.x;
    o4.y = (v.y - mu) * rstd * gv.y + bv.y;
    o4.z = (v.z - mu) * rstd * gv.z + bv.z;
    o4.w = (v.w - mu) * rstd * gv.w + bv.w;
    *(float4*)(out + (size_t)r * 1024 + tid * 4) = o4;
}

// ------------------------------------------------------------------ launch
extern "C" void kernel_launch(void* const* d_in, const int* in_sizes, int n_in,
                              void* d_out, int out_size, void* d_ws, size_t ws_size,
                              hipStream_t stream) {
    const float* x  = (const float*)d_in[0];
    const float* Wq = (const float*)d_in[1];
    const float* bq = (const float*)d_in[2];
    const float* Wk = (const float*)d_in[3];
    const float* bk = (const float*)d_in[4];
    const float* Wv = (const float*)d_in[5];
    const float* bv = (const float*)d_in[6];
    const float* Wo = (const float*)d_in[7];
    const float* bo = (const float*)d_in[8];
    const float* lg = (const float*)d_in[9];
    const float* lb = (const float*)d_in[10];
    float* out = (float*)d_out;

    char* ws = (char*)d_ws;
    u16* xb = (u16*)(ws + 0);
    u16* wt = (u16*)(ws + 16777216);
    u16* q  = (u16*)(ws + 25165824);
    u16* k  = (u16*)(ws + 41943040);
    u16* vt = (u16*)(ws + 75497472);
    u16* cx = (u16*)(ws + 92274688);
    float* y = (float*)(ws + 109051904);

    convert_x_kernel<<<4096, 256, 0, stream>>>(x, xb);
    convert_wt_kernel<<<dim3(16, 16, 4), 256, 0, stream>>>(Wq, Wk, Wv, Wo, wt);

    gemm_qkv256_kernel<<<384, 512, 0, stream>>>(xb, wt, bq, bk, bv, q, k, vt);
    attn_kernel<<<dim3(64, 8), 512, 0, stream>>>(q, k, vt, cx);
    gemm_wo_kernel<<<256, 512, 0, stream>>>(cx, wt + 3145728, bo, y, x);
    ln_kernel<<<8192, 256, 0, stream>>>(y, lg, lb, out);
}